// Round 13
// baseline (564.411 us; speedup 1.0000x reference)
//
#include <hip/hip_runtime.h>
#include <math.h>

#define NPTS 4096
#define BATCH 8
#define HIDD 512
#define ROWS 32768
#define R_ATT2 0.04f
#define INV_SQRT_D 0.08838834764831845f
#define LOG2E 1.4426950408889634f
#define NCOPY 8

typedef unsigned short u16;
typedef unsigned int u32;
typedef __attribute__((ext_vector_type(8))) short s8v;
typedef __attribute__((ext_vector_type(4))) float f4v;
typedef __attribute__((ext_vector_type(4))) u32 u4v;
typedef __attribute__((ext_vector_type(2))) u32 u2v;

__device__ __forceinline__ float u2f(u16 v) { return __uint_as_float(((u32)v) << 16); }
__device__ __forceinline__ u16 f2u(float f) {         // RNE fp32->bf16
  u32 u = __float_as_uint(f);
  return (u16)((u + 0x7fffu + ((u >> 16) & 1u)) >> 16);
}
// trunc-pack two fp32 into packed bf16 pair (1 lshr + 1 and_or)
__device__ __forceinline__ u32 packtrunc(float x0, float x1) {
  return (__float_as_uint(x1) & 0xFFFF0000u) | (__float_as_uint(x0) >> 16);
}
__device__ __forceinline__ float fast_exp2(float x) {
  float r;
  asm("v_exp_f32 %0, %1" : "=v"(r) : "v"(x));
  return r;
}
__device__ __forceinline__ s8v mk8(u32 a, u32 b, u32 c, u32 d) {
  union { u4v u; s8v s; } x;
  x.u = (u4v){a, b, c, d};
  return x.s;
}
// BN scale/shift from channel sums (N=32768)
__device__ __forceinline__ void bn_coef(float s, float q, float gam, float bet,
                                        float& sc, float& sh) {
  float mean = s * (1.f / 32768.f);
  float var = fmaxf(q * (1.f / 32768.f) - mean * mean, 0.f);
  float inv = rsqrtf(var + 1e-5f);
  sc = gam * inv;
  sh = bet - mean * sc;
}
// sum the NCOPY contention-spread copies of a channel sum
__device__ __forceinline__ void sum_copies(const float* __restrict__ ps,
                                           const float* __restrict__ pq,
                                           int ch, float& s, float& q) {
  s = 0.f; q = 0.f;
#pragma unroll
  for (int c = 0; c < NCOPY; ++c) {
    s += ps[c * 512 + ch];
    q += pq[c * 512 + ch];
  }
}

// ---------------------------------------------------------------------------
// G = wq^T @ wk (3x3)
__global__ void gram_k(const float* __restrict__ wq, const float* __restrict__ wk,
                       float* __restrict__ G) {
  int ab = threadIdx.x;
  if (ab < 9) {
    int a = ab / 3, b = ab % 3;
    float s = 0.f;
    for (int d = 0; d < 128; ++d) s = fmaf(wq[d * 3 + a], wk[d * 3 + b], s);
    G[ab] = s;
  }
}

// Fused per-stage prep: zw (wave-per-output) + ubuf/w1abf/w2bf conversions
// + zero the 4 channel-sum arrays (NCOPY copies each).
__global__ __launch_bounds__(256) void prep2_k(
    const float* __restrict__ z, const float* __restrict__ w1, int ldw,
    const float* __restrict__ b1, const float* __restrict__ w2,
    float* __restrict__ zwbuf, float* __restrict__ ubuf,
    u16* __restrict__ w1abf, u16* __restrict__ w2bf, int doW1a,
    float* __restrict__ psA, float* __restrict__ pqA,
    float* __restrict__ psB, float* __restrict__ pqB) {
  int wid = blockIdx.x * 4 + (threadIdx.x >> 6);   // 0..4095
  int lane = threadIdx.x & 63;
  {
    int b = wid >> 9, c = wid & 511;
    const float* zr = z + b * 512;
    const float* wr = w1 + (size_t)c * ldw;
    float acc = 0.f;
#pragma unroll
    for (int k = lane; k < 512; k += 64) acc = fmaf(zr[k], wr[k], acc);
#pragma unroll
    for (int off = 32; off; off >>= 1) acc += __shfl_down(acc, off);
    if (lane == 0) zwbuf[wid] = acc + b1[c];
  }
  int idx = blockIdx.x * 256 + threadIdx.x;        // 1024 blocks = 262144
  if (idx < 1536) {
    int a = idx >> 9, c = idx & 511;
    ubuf[idx] = w1[(size_t)c * ldw + 512 + a];
  }
  if (idx < NCOPY * 512) {
    psA[idx] = 0.f; pqA[idx] = 0.f;
    psB[idx] = 0.f; pqB[idx] = 0.f;
  }
  if (doW1a && idx < 65536) {
    int n = idx >> 7, k = idx & 127;
    w1abf[idx] = f2u(w1[(size_t)n * 643 + 515 + k]);
  }
  w2bf[idx] = f2u(w2[idx]);
}

// ---------------------------------------------------------------------------
// stage0 layer1 + fused BN stats: 16 rows per block (2048 slabs).
__global__ __launch_bounds__(256) void s0l1s_k(const float* __restrict__ tmpl,
                                               const float* __restrict__ u,
                                               const float* __restrict__ zw,
                                               u16* __restrict__ h,
                                               float* __restrict__ psum,
                                               float* __restrict__ psumsq) {
  __shared__ float Ls[4][512];
  __shared__ float Lq[4][512];
  int g = blockIdx.x;                 // slab 0..2047 (16 rows each)
  int wave = threadIdx.x >> 6, lane = threadIdx.x & 63;
  int b = g >> 8;                     // 256 slabs per batch
  int c0 = lane * 8;
  const float* zr = zw + b * 512 + c0;
  const float* u0 = u + c0;
  const float* u1 = u + 512 + c0;
  const float* u2 = u + 1024 + c0;
  float zv[8], u0v[8], u1v[8], u2v[8];
#pragma unroll
  for (int j = 0; j < 8; ++j) {
    zv[j] = zr[j]; u0v[j] = u0[j]; u1v[j] = u1[j]; u2v[j] = u2[j];
  }
  float s[8] = {0, 0, 0, 0, 0, 0, 0, 0}, q[8] = {0, 0, 0, 0, 0, 0, 0, 0};
  int row0 = g * 16 + wave * 4;
#pragma unroll
  for (int t = 0; t < 4; ++t) {
    int row = row0 + t;
    int n = row & (NPTS - 1);
    float tx = tmpl[n * 3], ty = tmpl[n * 3 + 1], tz = tmpl[n * 3 + 2];
    u32 outw[4];
#pragma unroll
    for (int jj = 0; jj < 4; ++jj) {
      float v0 = zv[2 * jj] + tx * u0v[2 * jj] + ty * u1v[2 * jj] + tz * u2v[2 * jj];
      float v1 = zv[2 * jj + 1] + tx * u0v[2 * jj + 1] + ty * u1v[2 * jj + 1] + tz * u2v[2 * jj + 1];
      outw[jj] = packtrunc(v0, v1);
      float r0 = u2f((u16)(outw[jj] & 0xffffu));
      float r1 = u2f((u16)(outw[jj] >> 16));
      s[2 * jj] += r0;     q[2 * jj] = fmaf(r0, r0, q[2 * jj]);
      s[2 * jj + 1] += r1; q[2 * jj + 1] = fmaf(r1, r1, q[2 * jj + 1]);
    }
    *(uint4*)(h + (size_t)row * 512 + c0) = *(const uint4*)outw;
  }
#pragma unroll
  for (int j = 0; j < 8; ++j) {
    Ls[wave][c0 + j] = s[j];
    Lq[wave][c0 + j] = q[j];
  }
  __syncthreads();
  int c2 = threadIdx.x * 2;
#pragma unroll
  for (int cc = 0; cc < 2; ++cc) {
    int c = c2 + cc;
    psum[g * 512 + c] = Ls[0][c] + Ls[1][c] + Ls[2][c] + Ls[3][c];
    psumsq[g * 512 + c] = Lq[0][c] + Lq[1][c] + Lq[2][c] + Lq[3][c];
  }
}

// Slab reduction (stage0 only): 2048 slabs -> channel sums into copy 0.
__global__ __launch_bounds__(256) void bn_red_k(
    const float* __restrict__ psum, const float* __restrict__ psumsq,
    float* __restrict__ psA, float* __restrict__ pqA) {
  int c = blockIdx.x * 4 + (threadIdx.x >> 6);   // 0..511
  int lane = threadIdx.x & 63;
  float s = 0.f, q = 0.f;
  for (int g = lane; g < 2048; g += 64) {
    s += psum[g * 512 + c];
    q += psumsq[g * 512 + c];
  }
#pragma unroll
  for (int off = 32; off; off >>= 1) {
    s += __shfl_down(s, off);
    q += __shfl_down(q, off);
  }
  if (lane == 0) {
    psA[c] = s;     // copy 0 (copies 1..NCOPY-1 stay zero from prep2)
    pqA[c] = q;
  }
}

// ---------------------------------------------------------------------------
// In-place BN+ReLU on h (bf16). BN coefficients computed INLINE from the
// NCOPY-spread channel sums (one-time prologue per thread; arrays L1-hot).
__global__ __launch_bounds__(256) void bnrelu_k(u16* __restrict__ h,
                                                const float* __restrict__ ps,
                                                const float* __restrict__ pq,
                                                const float* __restrict__ gamma,
                                                const float* __restrict__ beta) {
  int i0 = blockIdx.x * 256 + threadIdx.x;
  int k0 = (i0 * 8) & 511;
  float scv[8], shv[8];
#pragma unroll
  for (int j = 0; j < 8; ++j) {
    float s, q;
    sum_copies(ps, pq, k0 + j, s, q);
    bn_coef(s, q, gamma[k0 + j], beta[k0 + j], scv[j], shv[j]);
  }
  int nthreads = gridDim.x * 256;
  int total = ROWS * 512 / 8;   // 2,097,152 8-elem chunks
  for (int i = i0; i < total; i += nthreads) {
    uint4 v = *(const uint4*)(h + (size_t)i * 8);
    const u16* p = (const u16*)&v;
    u32 outw[4];
#pragma unroll
    for (int t = 0; t < 4; ++t) {
      float x0 = fmaxf(fmaf(u2f(p[2 * t]), scv[2 * t], shv[2 * t]), 0.f);
      float x1 = fmaxf(fmaf(u2f(p[2 * t + 1]), scv[2 * t + 1], shv[2 * t + 1]), 0.f);
      outw[t] = packtrunc(x0, x1);
    }
    *(uint4*)(h + (size_t)i * 8) = *(const uint4*)outw;
  }
}

// ---------------------------------------------------------------------------
// MFMA GEMM, 2-phase explicit double-buffer. BN-stat epilogue atomicAdds into
// NCOPY contention-spread channel-sum copies (r12: single-copy atomics cost
// ~+10us/dispatch from 256 same-address RMWs; 8 copies -> 32/address).
template <bool MODE1>
__global__ __launch_bounds__(256) void gemm_mfma_k(
    const u16* __restrict__ A, int lda, const u16* __restrict__ B, int ldb, int K,
    const float* __restrict__ bias, const float* __restrict__ zw,
    const float* __restrict__ u, const float4* __restrict__ c4,
    u16* __restrict__ C, float* __restrict__ psum, float* __restrict__ psumsq) {
  __shared__ u16 As[2][128 * 32];   // 2 x 8 KB
  __shared__ u16 Bs[2][128 * 32];
  int tid = threadIdx.x;
  int wave = tid >> 6, lane = tid & 63;
  int quad = lane >> 4, l16 = lane & 15;
  int m0 = blockIdx.x * 128, n0 = blockIdx.y * 128;
  int wm = (wave & 1) * 64, wn = (wave >> 1) * 64;
  int srow0 = lane >> 2;          // 0..15 within chunk
  int sc8 = (lane & 3) * 8;       // k-subcol *8
  f4v acc[4][4];
#pragma unroll
  for (int mi = 0; mi < 4; ++mi)
#pragma unroll
    for (int ni = 0; ni < 4; ++ni) acc[mi][ni] = (f4v){0.f, 0.f, 0.f, 0.f};

  int chunk = wave * 2;
  int row0 = chunk * 16 + srow0;
  const u16* gA0 = A + (size_t)(m0 + row0) * lda + sc8;
  const u16* gA1 = A + (size_t)(m0 + row0 + 16) * lda + sc8;
  const u16* gB0 = B + (size_t)(n0 + row0) * ldb + sc8;
  const u16* gB1 = B + (size_t)(n0 + row0 + 16) * ldb + sc8;

  auto stage = [&](int nb, int k0) {
    __builtin_amdgcn_global_load_lds(
        (const __attribute__((address_space(1))) void*)(gA0 + k0),
        (__attribute__((address_space(3))) void*)(As[nb] + chunk * 512), 16, 0, 0);
    __builtin_amdgcn_global_load_lds(
        (const __attribute__((address_space(1))) void*)(gA1 + k0),
        (__attribute__((address_space(3))) void*)(As[nb] + (chunk + 1) * 512), 16, 0, 0);
    __builtin_amdgcn_global_load_lds(
        (const __attribute__((address_space(1))) void*)(gB0 + k0),
        (__attribute__((address_space(3))) void*)(Bs[nb] + chunk * 512), 16, 0, 0);
    __builtin_amdgcn_global_load_lds(
        (const __attribute__((address_space(1))) void*)(gB1 + k0),
        (__attribute__((address_space(3))) void*)(Bs[nb] + (chunk + 1) * 512), 16, 0, 0);
  };

  int NT = K >> 5;
  stage(0, 0);
  __syncthreads();                 // buf0 ready
  int cur = 0;
  for (int t = 0; t < NT; ++t) {
    if (t + 1 < NT) stage(cur ^ 1, (t + 1) * 32);   // loads fly under compute
    s8v af[4], bfv[4];
#pragma unroll
    for (int mi = 0; mi < 4; ++mi)
      af[mi] = *(const s8v*)&As[cur][(wm + mi * 16 + l16) * 32 + quad * 8];
#pragma unroll
    for (int ni = 0; ni < 4; ++ni)
      bfv[ni] = *(const s8v*)&Bs[cur][(wn + ni * 16 + l16) * 32 + quad * 8];
#pragma unroll
    for (int mi = 0; mi < 4; ++mi)
#pragma unroll
      for (int ni = 0; ni < 4; ++ni)
        acc[mi][ni] = __builtin_amdgcn_mfma_f32_16x16x32_bf16(
            af[mi], bfv[ni], acc[mi][ni], 0, 0, 0);
    __syncthreads();               // drains next-tile loads + orders reads
    cur ^= 1;
  }

  // epilogue + per-thread column partials
  int batch = m0 >> 12;
  float e0[4], e1[4], e2[4], e3[4];
  float ps[4] = {0, 0, 0, 0}, pq[4] = {0, 0, 0, 0};
#pragma unroll
  for (int ni = 0; ni < 4; ++ni) {
    int gn = n0 + wn + ni * 16 + l16;
    if (MODE1) {
      e0[ni] = zw[batch * 512 + gn];
      e1[ni] = u[gn];
      e2[ni] = u[512 + gn];
      e3[ni] = u[1024 + gn];
    } else {
      e0[ni] = bias[gn];
    }
  }
#pragma unroll
  for (int mi = 0; mi < 4; ++mi) {
#pragma unroll
    for (int reg = 0; reg < 4; ++reg) {
      int gm = m0 + wm + mi * 16 + quad * 4 + reg;
      float cx = 0.f, cy = 0.f, cz = 0.f;
      if (MODE1) {
        float4 p = c4[gm];
        cx = p.x; cy = p.y; cz = p.z;
      }
#pragma unroll
      for (int ni = 0; ni < 4; ++ni) {
        int gn = n0 + wn + ni * 16 + l16;
        float v = acc[mi][ni][reg] + e0[ni];
        if (MODE1) v += cx * e1[ni] + cy * e2[ni] + cz * e3[ni];
        u16 r = f2u(v);
        C[(size_t)gm * 512 + gn] = r;
        float vr = u2f(r);
        ps[ni] += vr;
        pq[ni] = fmaf(vr, vr, pq[ni]);
      }
    }
  }
  // block-level column reduction via LDS scratch (As=sum, Bs=sumsq)
  float* Lps = (float*)As;
  float* Lpq = (float*)Bs;
#pragma unroll
  for (int ni = 0; ni < 4; ++ni) {
    Lps[((wave * 4 + quad) * 4 + ni) * 16 + l16] = ps[ni];
    Lpq[((wave * 4 + quad) * 4 + ni) * 16 + l16] = pq[ni];
  }
  __syncthreads();
  if (tid < 128) {
    int wn2 = tid >> 6, rem = tid & 63;
    int nni = rem >> 4, ll = rem & 15;
    int gn = n0 + wn2 * 64 + nni * 16 + ll;
    float s = 0.f, q = 0.f;
#pragma unroll
    for (int wv = 0; wv < 2; ++wv)
#pragma unroll
      for (int qd = 0; qd < 4; ++qd) {
        int w2 = wn2 * 2 + wv;
        s += Lps[((w2 * 4 + qd) * 4 + nni) * 16 + ll];
        q += Lpq[((w2 * 4 + qd) * 4 + nni) * 16 + ll];
      }
    int cp = (blockIdx.x & (NCOPY - 1)) * 512;
    atomicAdd(&psum[cp + gn], s);
    atomicAdd(&psumsq[cp + gn], q);
  }
}

// ---------------------------------------------------------------------------
// layer3 (BN inline from NCOPY-spread channel sums) + fused attention
// coord-prep (frag + transposed-coords tables).
__global__ __launch_bounds__(256) void l3_k(const u16* __restrict__ h,
                                            const float* __restrict__ ps,
                                            const float* __restrict__ pq,
                                            const float* __restrict__ gamma,
                                            const float* __restrict__ beta,
                                            const float* __restrict__ w3,
                                            const float* __restrict__ b3,
                                            float4* __restrict__ c4out,
                                            float* __restrict__ fout,
                                            u4v* __restrict__ frag,
                                            u16* __restrict__ ctg) {
  int wid = blockIdx.x * 4 + (threadIdx.x >> 6);
  int lane = threadIdx.x & 63;
  int k0 = lane * 8;
  float scv[8], shv[8];
#pragma unroll
  for (int j = 0; j < 8; ++j) {
    float s, q;
    sum_copies(ps, pq, k0 + j, s, q);
    bn_coef(s, q, gamma[k0 + j], beta[k0 + j], scv[j], shv[j]);
  }
  uint4 hv = *(const uint4*)(h + (size_t)wid * 512 + k0);
  const u16* hp = (const u16*)&hv;
  float a0 = 0, a1 = 0, a2 = 0;
#pragma unroll
  for (int j = 0; j < 8; ++j) {
    float x = fmaxf(fmaf(u2f(hp[j]), scv[j], shv[j]), 0.f);
    a0 = fmaf(x, w3[k0 + j], a0);
    a1 = fmaf(x, w3[512 + k0 + j], a1);
    a2 = fmaf(x, w3[1024 + k0 + j], a2);
  }
#pragma unroll
  for (int off = 32; off; off >>= 1) {
    a0 += __shfl_down(a0, off);
    a1 += __shfl_down(a1, off);
    a2 += __shfl_down(a2, off);
  }
  if (lane == 0) {
    a0 += b3[0]; a1 += b3[1]; a2 += b3[2];
    if (c4out) {
      float sq = a0 * a0 + a1 * a1 + a2 * a2;
      c4out[wid] = make_float4(a0, a1, a2, sq);
      // fused cprep: hi/lo bf16 A-frag + transposed PV coords (row0 = ones)
      float nhw = -0.5f * sq;
      u16 hx = f2u(a0), hy = f2u(a1), hz = f2u(a2), hw = f2u(nhw);
      u16 lx = f2u(a0 - u2f(hx)), ly = f2u(a1 - u2f(hy));
      u16 lz = f2u(a2 - u2f(hz)), lw = f2u(nhw - u2f(hw));
      u32 h01 = (u32)hx | ((u32)hy << 16), h23 = (u32)hz | ((u32)hw << 16);
      u32 l01 = (u32)lx | ((u32)ly << 16), l23 = (u32)lz | ((u32)lw << 16);
      frag[wid] = (u4v){h01, h23, l01, l23};
      int chunk = wid >> 5, p32 = wid & 31;
      u16* basep = ctg + (size_t)chunk * 128;    // 4 rows x 32 u16
      basep[p32] = 0x3F80;                       // ones row (c=0)
      basep[32 + p32] = hx;
      basep[64 + p32] = hy;
      basep[96 + p32] = hz;
    }
    if (fout) {
      fout[(size_t)wid * 3 + 0] = a0;
      fout[(size_t)wid * 3 + 1] = a1;
      fout[(size_t)wid * 3 + 2] = a2;
    }
  }
}

// ---------------------------------------------------------------------------
// MFMA flash attention. Block = 512 thr (8 waves), 32 queries/block (1024
// blocks). SIMD-issue-bound at ~45us. Score tile 16p x 16q via
// mfma_16x16x32_bf16 with compensated hi/lo split in spare K-slots
// (fp32-grade mask). Point-side fragments precomputed (fused into l3).
// e values trunc-packed bf16 via wave-private LDS (80B-padded rows).
__global__ __launch_bounds__(512) void attnm_k(const float4* __restrict__ c4,
                                               const u4v* __restrict__ frag,
                                               const u16* __restrict__ ctg,
                                               const float* __restrict__ G,
                                               const float* __restrict__ wv,
                                               u16* __restrict__ attnb) {
  // LDS: ebuf 8w*2560=20480 | fin 4096  => 24 KB
  __shared__ __align__(16) char lds[20480 + 4096];
  int wave = threadIdx.x >> 6, lane = threadIdx.x & 63;
  int g = lane >> 4, q16 = lane & 15;
  int qbase = blockIdx.x * 32;          // 32 consecutive queries, same batch
  int b = qbase >> 12;
  int pt0 = wave * 512;
  char* ebuf = lds + wave * 2560;       // 2 s-sets x 16 q x 80 B
  float* fin = (float*)(lds + 20480);
  int chunk0 = b * 128 + (pt0 >> 5);    // global 32-pt chunk base for this wave

  // ---- query-side B-frags (2 sets x 16 q) ----
  float Gr[9];
#pragma unroll
  for (int i = 0; i < 9; ++i) Gr[i] = G[i];
  u32 bh0[2], bh1[2], bh2[2], bh3[2];   // dm-B words
  u32 sh0[2], sh1[2], sh2[2], sh3[2];   // s2-B words
  float thr[2];
#pragma unroll
  for (int s = 0; s < 2; ++s) {
    float4 cq = c4[qbase + s * 16 + q16];
    thr[s] = 0.5f * (cq.w - R_ATT2);
    u16 hx = f2u(cq.x), hy = f2u(cq.y), hz = f2u(cq.z);
    u16 lx = f2u(cq.x - u2f(hx)), ly = f2u(cq.y - u2f(hy)), lz = f2u(cq.z - u2f(hz));
    u32 h01 = (u32)hx | ((u32)hy << 16);
    u32 h23 = (u32)hz | (0x3F80u << 16);     // [cz, 1.0]
    u32 l01 = (u32)lx | ((u32)ly << 16);
    u32 l23 = (u32)lz;                        // [lz, 0]
    bh0[s] = (g <= 1) ? h01 : 0u;
    bh1[s] = (g <= 1) ? h23 : 0u;
    bh2[s] = (g == 0) ? l01 : 0u;
    bh3[s] = (g == 0) ? l23 : 0u;
    const float SC = INV_SQRT_D * LOG2E;
    float g0v = (cq.x * Gr[0] + cq.y * Gr[3] + cq.z * Gr[6]) * SC;
    float g1v = (cq.x * Gr[1] + cq.y * Gr[4] + cq.z * Gr[7]) * SC;
    float g2v = (cq.x * Gr[2] + cq.y * Gr[5] + cq.z * Gr[8]) * SC;
    u16 ghx = f2u(g0v), ghy = f2u(g1v), ghz = f2u(g2v);
    u16 glx = f2u(g0v - u2f(ghx)), gly = f2u(g1v - u2f(ghy)), glz = f2u(g2v - u2f(ghz));
    u32 gh01 = (u32)ghx | ((u32)ghy << 16);
    u32 gh23 = (u32)ghz;                      // [gz, 0]
    u32 gl01 = (u32)glx | ((u32)gly << 16);
    u32 gl23 = (u32)glz;
    sh0[s] = (g <= 1) ? gh01 : 0u;
    sh1[s] = (g <= 1) ? gh23 : 0u;
    sh2[s] = (g == 0) ? gl01 : 0u;
    sh3[s] = (g == 0) ? gl23 : 0u;
  }

  f4v pvAcc[2];
#pragma unroll
  for (int s = 0; s < 2; ++s) pvAcc[s] = (f4v){0.f, 0.f, 0.f, 0.f};

  int csw = g ^ (q16 & 3);              // swizzled read chunk (PV A-frag)
  for (int w = 0; w < 16; ++w) {        // 16 windows x 32 pts
#pragma unroll
    for (int tp = 0; tp < 2; ++tp) {
      int p = pt0 + w * 32 + tp * 16 + q16;
      u4v f = frag[(size_t)b * NPTS + p];
      u32 a0 = (g == 0) ? f.x : ((g == 1) ? f.z : 0u);
      u32 a1 = (g == 0) ? f.y : ((g == 1) ? f.w : 0u);
      u32 a2 = (g == 0) ? f.x : 0u;
      u32 a3 = (g == 0) ? f.y : 0u;
      s8v av = mk8(a0, a1, a2, a3);
      int wsw = ((tp * 2 + (g >> 1)) ^ (q16 & 3)) * 16 + (g & 1) * 8;
#pragma unroll
      for (int s = 0; s < 2; ++s) {
        f4v z4 = (f4v){0.f, 0.f, 0.f, 0.f};
        f4v dmv = __builtin_amdgcn_mfma_f32_16x16x32_bf16(
            av, mk8(bh0[s], bh1[s], bh2[s], bh3[s]), z4, 0, 0, 0);
        f4v s2v = __builtin_amdgcn_mfma_f32_16x16x32_bf16(
            av, mk8(sh0[s], sh1[s], sh2[s], sh3[s]), z4, 0, 0, 0);
        float e0 = (dmv[0] >= thr[s]) ? fast_exp2(s2v[0]) : 0.f;
        float e1 = (dmv[1] >= thr[s]) ? fast_exp2(s2v[1]) : 0.f;
        float e2 = (dmv[2] >= thr[s]) ? fast_exp2(s2v[2]) : 0.f;
        float e3 = (dmv[3] >= thr[s]) ? fast_exp2(s2v[3]) : 0.f;
        u2v ew = (u2v){packtrunc(e0, e1), packtrunc(e2, e3)};
        *(u2v*)(ebuf + s * 1280 + q16 * 80 + wsw) = ew;
      }
    }
    // PV B-frag: lane (g, c=q16&3): coord row c of pts g*8..g*8+7 (row0=ones)
    const u16* ctb = ctg + (size_t)(chunk0 + w) * 128 + (q16 & 3) * 32 + g * 8;
    u4v bt = *(const u4v*)ctb;
    s8v pvB = mk8(bt.x, bt.y, bt.z, bt.w);
#pragma unroll
    for (int s = 0; s < 2; ++s) {
      u4v at = *(const u4v*)(ebuf + s * 1280 + q16 * 80 + csw * 16);
      pvAcc[s] = __builtin_amdgcn_mfma_f32_16x16x32_bf16(
          mk8(at.x, at.y, at.z, at.w), pvB, pvAcc[s], 0, 0, 0);
    }
  }

  // ---- combine 8 waves, normalize, project to attnb ----
  if (q16 < 4) {
#pragma unroll
    for (int s = 0; s < 2; ++s)
#pragma unroll
      for (int r = 0; r < 4; ++r)
        fin[wave * 128 + (s * 16 + g * 4 + r) * 4 + q16] = pvAcc[s][r];
  }
  __syncthreads();
  float* comb = (float*)lds;   // 128 floats, reuses ebuf region
  int t = threadIdx.x;
  if (t < 128) {
    int qb = t >> 2, c = t & 3;
    float acc = 0.f;
#pragma unroll
    for (int wv8 = 0; wv8 < 8; ++wv8) acc += fin[wv8 * 128 + qb * 4 + c];
    comb[qb * 4 + c] = acc;
  }
  __syncthreads();
#pragma unroll
  for (int it = 0; it < 4; ++it) {
    int task = t + it * 512;            // 2048 tasks: 32 q x 64 d-pairs
    int qb = task >> 6, dp = task & 63;
    float sw = comb[qb * 4 + 0];
    float sx = comb[qb * 4 + 1];
    float sy = comb[qb * 4 + 2];
    float sz = comb[qb * 4 + 3];
    float inv = 1.f / sw;
    float ox = sx * inv, oy = sy * inv, oz = sz * inv;
    int d0 = dp * 2;
    float v0 = ox * wv[d0 * 3] + oy * wv[d0 * 3 + 1] + oz * wv[d0 * 3 + 2];
    float v1 = ox * wv[d0 * 3 + 3] + oy * wv[d0 * 3 + 4] + oz * wv[d0 * 3 + 5];
    u32 pack = (u32)f2u(v0) | ((u32)f2u(v1) << 16);
    *(u32*)(attnb + (size_t)(qbase + qb) * 128 + d0) = pack;
  }
}

// ---------------------------------------------------------------------------
extern "C" void kernel_launch(void* const* d_in, const int* in_sizes, int n_in,
                              void* d_out, int out_size, void* d_ws, size_t ws_size,
                              hipStream_t stream) {
  const float* z = (const float*)d_in[0];
  const float* tmpl = (const float*)d_in[1];
  const float* wq = (const float*)d_in[2];
  const float* wk = (const float*)d_in[3];
  const float* wv = (const float*)d_in[4];
  const float* sw[3][10];
  for (int s = 0; s < 3; ++s)
    for (int j = 0; j < 10; ++j) sw[s][j] = (const float*)d_in[5 + s * 10 + j];
  // j: 0=w1 1=b1 2=g1 3=be1 4=w2 5=b2 6=g2 7=be2 8=w3 9=b3

  char* base = (char*)d_ws;
  size_t off = 0;
  auto alloc = [&](size_t bytes) -> void* {
    void* p = base + off;
    off = (off + bytes + 255) & ~(size_t)255;
    return p;
  };
  u16* hA = (u16*)alloc((size_t)ROWS * 512 * 2);        // 33.55 MB
  u16* hB = (u16*)alloc((size_t)ROWS * 512 * 2);        // 33.55 MB
  u16* attnb = (u16*)alloc((size_t)ROWS * 128 * 2);     //  8.39 MB
  float4* c4 = (float4*)alloc((size_t)ROWS * 16);       //  0.52 MB
  float* psum = (float*)alloc(2048 * 512 * 4);          //  4.19 MB (s0 slabs)
  float* psumsq = (float*)alloc(2048 * 512 * 4);        //  4.19 MB
  float* zwbuf = (float*)alloc(4096 * 4);
  float* psA = (float*)alloc(NCOPY * 512 * 4);          // channel sums (h1)
  float* pqA = (float*)alloc(NCOPY * 512 * 4);
  float* psB = (float*)alloc(NCOPY * 512 * 4);          // channel sums (h2)
  float* pqB = (float*)alloc(NCOPY * 512 * 4);
  float* G = (float*)alloc(256);
  u16* w1abf = (u16*)alloc(512 * 128 * 2);
  u16* w2bf = (u16*)alloc(512 * 512 * 2);
  float* ubuf = (float*)alloc(1536 * 4);
  u4v* fragb = (u4v*)alloc((size_t)ROWS * 16);          //  0.52 MB
  u16* ctg = (u16*)alloc((size_t)1024 * 128 * 2);       //  0.26 MB

  gram_k<<<1, 64, 0, stream>>>(wq, wk, G);

  for (int s = 0; s < 3; ++s) {
    int ldw = (s == 0) ? 515 : 643;
    prep2_k<<<1024, 256, 0, stream>>>(z, sw[s][0], ldw, sw[s][1], sw[s][4],
                                      zwbuf, ubuf, w1abf, w2bf, s == 0 ? 0 : 1,
                                      psA, pqA, psB, pqB);
    if (s == 0) {
      // layer1 + slab BN stats, then slab->channel-sum reduction
      s0l1s_k<<<2048, 256, 0, stream>>>(tmpl, ubuf, zwbuf, hA, psum, psumsq);
      bn_red_k<<<128, 256, 0, stream>>>(psum, psumsq, psA, pqA);
    } else {
      // GEMM1: h1 = attnb @ w1a^T + (zw + coords-rank3); spread-atomic stats
      gemm_mfma_k<true><<<dim3(256, 4), 256, 0, stream>>>(
          attnb, 128, w1abf, 128, 128, nullptr, zwbuf, ubuf, c4,
          hA, psA, pqA);
    }
    // BN+ReLU in-place on hA (BN coefs inline from psA copies), then GEMM2
    // with direct global_load_lds staging and spread-atomic h2 stats.
    bnrelu_k<<<2048, 256, 0, stream>>>(hA, psA, pqA, sw[s][2], sw[s][3]);
    gemm_mfma_k<false><<<dim3(256, 4), 256, 0, stream>>>(
        hA, 512, w2bf, 512, 512, sw[s][5], nullptr, nullptr, nullptr,
        hB, psB, pqB);
    bool last = (s == 2);
    // layer3 with inline BN (from psB copies) + fused attention coord-prep
    l3_k<<<8192, 256, 0, stream>>>(hB, psB, pqB, sw[s][6], sw[s][7],
                                   sw[s][8], sw[s][9],
                                   last ? nullptr : c4,
                                   last ? (float*)d_out : nullptr,
                                   fragb, ctg);
    if (!last) {
      attnm_k<<<1024, 512, 0, stream>>>(c4, fragb, ctg, G, wv, attnb);
    }
  }
}

// Round 14
// 457.409 us; speedup vs baseline: 1.2339x; 1.2339x over previous
//
#include <hip/hip_runtime.h>
#include <math.h>

#define NPTS 4096
#define BATCH 8
#define HIDD 512
#define ROWS 32768
#define R_ATT2 0.04f
#define INV_SQRT_D 0.08838834764831845f
#define LOG2E 1.4426950408889634f

typedef unsigned short u16;
typedef unsigned int u32;
typedef __attribute__((ext_vector_type(8))) short s8v;
typedef __attribute__((ext_vector_type(4))) float f4v;
typedef __attribute__((ext_vector_type(4))) u32 u4v;
typedef __attribute__((ext_vector_type(2))) u32 u2v;

__device__ __forceinline__ float u2f(u16 v) { return __uint_as_float(((u32)v) << 16); }
__device__ __forceinline__ u16 f2u(float f) {         // RNE fp32->bf16
  u32 u = __float_as_uint(f);
  return (u16)((u + 0x7fffu + ((u >> 16) & 1u)) >> 16);
}
// trunc-pack two fp32 into packed bf16 pair (1 lshr + 1 and_or)
__device__ __forceinline__ u32 packtrunc(float x0, float x1) {
  return (__float_as_uint(x1) & 0xFFFF0000u) | (__float_as_uint(x0) >> 16);
}
__device__ __forceinline__ float fast_exp2(float x) {
  float r;
  asm("v_exp_f32 %0, %1" : "=v"(r) : "v"(x));
  return r;
}
__device__ __forceinline__ s8v mk8(u32 a, u32 b, u32 c, u32 d) {
  union { u4v u; s8v s; } x;
  x.u = (u4v){a, b, c, d};
  return x.s;
}

// ---------------------------------------------------------------------------
// G = wq^T @ wk (3x3)
__global__ void gram_k(const float* __restrict__ wq, const float* __restrict__ wk,
                       float* __restrict__ G) {
  int ab = threadIdx.x;
  if (ab < 9) {
    int a = ab / 3, b = ab % 3;
    float s = 0.f;
    for (int d = 0; d < 128; ++d) s = fmaf(wq[d * 3 + a], wk[d * 3 + b], s);
    G[ab] = s;
  }
}

// Fused per-stage prep: zw (wave-per-output) + ubuf/w1abf/w2bf conversions.
__global__ __launch_bounds__(256) void prep2_k(
    const float* __restrict__ z, const float* __restrict__ w1, int ldw,
    const float* __restrict__ b1, const float* __restrict__ w2,
    float* __restrict__ zwbuf, float* __restrict__ ubuf,
    u16* __restrict__ w1abf, u16* __restrict__ w2bf, int doW1a) {
  int wid = blockIdx.x * 4 + (threadIdx.x >> 6);   // 0..4095
  int lane = threadIdx.x & 63;
  {
    int b = wid >> 9, c = wid & 511;
    const float* zr = z + b * 512;
    const float* wr = w1 + (size_t)c * ldw;
    float acc = 0.f;
#pragma unroll
    for (int k = lane; k < 512; k += 64) acc = fmaf(zr[k], wr[k], acc);
#pragma unroll
    for (int off = 32; off; off >>= 1) acc += __shfl_down(acc, off);
    if (lane == 0) zwbuf[wid] = acc + b1[c];
  }
  int idx = blockIdx.x * 256 + threadIdx.x;        // 1024 blocks = 262144
  if (idx < 1536) {
    int a = idx >> 9, c = idx & 511;
    ubuf[idx] = w1[(size_t)c * ldw + 512 + a];
  }
  if (doW1a && idx < 65536) {
    int n = idx >> 7, k = idx & 127;
    w1abf[idx] = f2u(w1[(size_t)n * 643 + 515 + k]);
  }
  w2bf[idx] = f2u(w2[idx]);
}

// ---------------------------------------------------------------------------
// stage0 layer1 + fused BN stats: 16 rows per block (2048 slabs).
__global__ __launch_bounds__(256) void s0l1s_k(const float* __restrict__ tmpl,
                                               const float* __restrict__ u,
                                               const float* __restrict__ zw,
                                               u16* __restrict__ h,
                                               float* __restrict__ psum,
                                               float* __restrict__ psumsq) {
  __shared__ float Ls[4][512];
  __shared__ float Lq[4][512];
  int g = blockIdx.x;                 // slab 0..2047 (16 rows each)
  int wave = threadIdx.x >> 6, lane = threadIdx.x & 63;
  int b = g >> 8;                     // 256 slabs per batch
  int c0 = lane * 8;
  const float* zr = zw + b * 512 + c0;
  const float* u0 = u + c0;
  const float* u1 = u + 512 + c0;
  const float* u2 = u + 1024 + c0;
  float zv[8], u0v[8], u1v[8], u2v[8];
#pragma unroll
  for (int j = 0; j < 8; ++j) {
    zv[j] = zr[j]; u0v[j] = u0[j]; u1v[j] = u1[j]; u2v[j] = u2[j];
  }
  float s[8] = {0, 0, 0, 0, 0, 0, 0, 0}, q[8] = {0, 0, 0, 0, 0, 0, 0, 0};
  int row0 = g * 16 + wave * 4;
#pragma unroll
  for (int t = 0; t < 4; ++t) {
    int row = row0 + t;
    int n = row & (NPTS - 1);
    float tx = tmpl[n * 3], ty = tmpl[n * 3 + 1], tz = tmpl[n * 3 + 2];
    u32 outw[4];
#pragma unroll
    for (int jj = 0; jj < 4; ++jj) {
      float v0 = zv[2 * jj] + tx * u0v[2 * jj] + ty * u1v[2 * jj] + tz * u2v[2 * jj];
      float v1 = zv[2 * jj + 1] + tx * u0v[2 * jj + 1] + ty * u1v[2 * jj + 1] + tz * u2v[2 * jj + 1];
      outw[jj] = packtrunc(v0, v1);
      float r0 = u2f((u16)(outw[jj] & 0xffffu));
      float r1 = u2f((u16)(outw[jj] >> 16));
      s[2 * jj] += r0;     q[2 * jj] = fmaf(r0, r0, q[2 * jj]);
      s[2 * jj + 1] += r1; q[2 * jj + 1] = fmaf(r1, r1, q[2 * jj + 1]);
    }
    *(uint4*)(h + (size_t)row * 512 + c0) = *(const uint4*)outw;
  }
#pragma unroll
  for (int j = 0; j < 8; ++j) {
    Ls[wave][c0 + j] = s[j];
    Lq[wave][c0 + j] = q[j];
  }
  __syncthreads();
  int c2 = threadIdx.x * 2;
#pragma unroll
  for (int cc = 0; cc < 2; ++cc) {
    int c = c2 + cc;
    psum[g * 512 + c] = Ls[0][c] + Ls[1][c] + Ls[2][c] + Ls[3][c];
    psumsq[g * 512 + c] = Lq[0][c] + Lq[1][c] + Lq[2][c] + Lq[3][c];
  }
}

// ---------------------------------------------------------------------------
// In-place BN+ReLU on h (bf16), trunc-pack.
__global__ __launch_bounds__(256) void bnrelu_k(u16* __restrict__ h,
                                                const float* __restrict__ sc,
                                                const float* __restrict__ sh) {
  int nthreads = gridDim.x * 256;
  int total = ROWS * 512 / 8;   // 2,097,152 8-elem chunks
  for (int i = blockIdx.x * 256 + threadIdx.x; i < total; i += nthreads) {
    int k0 = (i * 8) & 511;
    uint4 v = *(const uint4*)(h + (size_t)i * 8);
    const u16* p = (const u16*)&v;
    u32 outw[4];
#pragma unroll
    for (int t = 0; t < 4; ++t) {
      float x0 = fmaxf(fmaf(u2f(p[2 * t]), sc[k0 + 2 * t], sh[k0 + 2 * t]), 0.f);
      float x1 = fmaxf(fmaf(u2f(p[2 * t + 1]), sc[k0 + 2 * t + 1], sh[k0 + 2 * t + 1]), 0.f);
      outw[t] = packtrunc(x0, x1);
    }
    *(uint4*)(h + (size_t)i * 8) = *(const uint4*)outw;
  }
}

// ---------------------------------------------------------------------------
// MFMA GEMM, 2-phase explicit double-buffer: issue next-tile global_load_lds
// BEFORE computing the current tile, one __syncthreads per K-step.
// Fused BN-stats epilogue (slab writes; atomics measured regressive r12/r13).
template <bool MODE1>
__global__ __launch_bounds__(256) void gemm_mfma_k(
    const u16* __restrict__ A, int lda, const u16* __restrict__ B, int ldb, int K,
    const float* __restrict__ bias, const float* __restrict__ zw,
    const float* __restrict__ u, const float4* __restrict__ c4,
    u16* __restrict__ C, float* __restrict__ psum, float* __restrict__ psumsq) {
  __shared__ u16 As[2][128 * 32];   // 2 x 8 KB
  __shared__ u16 Bs[2][128 * 32];
  int tid = threadIdx.x;
  int wave = tid >> 6, lane = tid & 63;
  int quad = lane >> 4, l16 = lane & 15;
  int m0 = blockIdx.x * 128, n0 = blockIdx.y * 128;
  int wm = (wave & 1) * 64, wn = (wave >> 1) * 64;
  int srow0 = lane >> 2;          // 0..15 within chunk
  int sc8 = (lane & 3) * 8;       // k-subcol *8
  f4v acc[4][4];
#pragma unroll
  for (int mi = 0; mi < 4; ++mi)
#pragma unroll
    for (int ni = 0; ni < 4; ++ni) acc[mi][ni] = (f4v){0.f, 0.f, 0.f, 0.f};

  int chunk = wave * 2;
  int row0 = chunk * 16 + srow0;
  const u16* gA0 = A + (size_t)(m0 + row0) * lda + sc8;
  const u16* gA1 = A + (size_t)(m0 + row0 + 16) * lda + sc8;
  const u16* gB0 = B + (size_t)(n0 + row0) * ldb + sc8;
  const u16* gB1 = B + (size_t)(n0 + row0 + 16) * ldb + sc8;

  auto stage = [&](int nb, int k0) {
    __builtin_amdgcn_global_load_lds(
        (const __attribute__((address_space(1))) void*)(gA0 + k0),
        (__attribute__((address_space(3))) void*)(As[nb] + chunk * 512), 16, 0, 0);
    __builtin_amdgcn_global_load_lds(
        (const __attribute__((address_space(1))) void*)(gA1 + k0),
        (__attribute__((address_space(3))) void*)(As[nb] + (chunk + 1) * 512), 16, 0, 0);
    __builtin_amdgcn_global_load_lds(
        (const __attribute__((address_space(1))) void*)(gB0 + k0),
        (__attribute__((address_space(3))) void*)(Bs[nb] + chunk * 512), 16, 0, 0);
    __builtin_amdgcn_global_load_lds(
        (const __attribute__((address_space(1))) void*)(gB1 + k0),
        (__attribute__((address_space(3))) void*)(Bs[nb] + (chunk + 1) * 512), 16, 0, 0);
  };

  int NT = K >> 5;
  stage(0, 0);
  __syncthreads();                 // buf0 ready
  int cur = 0;
  for (int t = 0; t < NT; ++t) {
    if (t + 1 < NT) stage(cur ^ 1, (t + 1) * 32);   // loads fly under compute
    s8v af[4], bfv[4];
#pragma unroll
    for (int mi = 0; mi < 4; ++mi)
      af[mi] = *(const s8v*)&As[cur][(wm + mi * 16 + l16) * 32 + quad * 8];
#pragma unroll
    for (int ni = 0; ni < 4; ++ni)
      bfv[ni] = *(const s8v*)&Bs[cur][(wn + ni * 16 + l16) * 32 + quad * 8];
#pragma unroll
    for (int mi = 0; mi < 4; ++mi)
#pragma unroll
      for (int ni = 0; ni < 4; ++ni)
        acc[mi][ni] = __builtin_amdgcn_mfma_f32_16x16x32_bf16(
            af[mi], bfv[ni], acc[mi][ni], 0, 0, 0);
    __syncthreads();               // drains next-tile loads + orders reads
    cur ^= 1;
  }

  // epilogue + per-thread column partials
  int batch = m0 >> 12;
  float e0[4], e1[4], e2[4], e3[4];
  float ps[4] = {0, 0, 0, 0}, pq[4] = {0, 0, 0, 0};
#pragma unroll
  for (int ni = 0; ni < 4; ++ni) {
    int gn = n0 + wn + ni * 16 + l16;
    if (MODE1) {
      e0[ni] = zw[batch * 512 + gn];
      e1[ni] = u[gn];
      e2[ni] = u[512 + gn];
      e3[ni] = u[1024 + gn];
    } else {
      e0[ni] = bias[gn];
    }
  }
#pragma unroll
  for (int mi = 0; mi < 4; ++mi) {
#pragma unroll
    for (int reg = 0; reg < 4; ++reg) {
      int gm = m0 + wm + mi * 16 + quad * 4 + reg;
      float cx = 0.f, cy = 0.f, cz = 0.f;
      if (MODE1) {
        float4 p = c4[gm];
        cx = p.x; cy = p.y; cz = p.z;
      }
#pragma unroll
      for (int ni = 0; ni < 4; ++ni) {
        int gn = n0 + wn + ni * 16 + l16;
        float v = acc[mi][ni][reg] + e0[ni];
        if (MODE1) v += cx * e1[ni] + cy * e2[ni] + cz * e3[ni];
        u16 r = f2u(v);
        C[(size_t)gm * 512 + gn] = r;
        float vr = u2f(r);
        ps[ni] += vr;
        pq[ni] = fmaf(vr, vr, pq[ni]);
      }
    }
  }
  // block-level column reduction via LDS scratch (As=sum, Bs=sumsq)
  float* Lps = (float*)As;
  float* Lpq = (float*)Bs;
#pragma unroll
  for (int ni = 0; ni < 4; ++ni) {
    Lps[((wave * 4 + quad) * 4 + ni) * 16 + l16] = ps[ni];
    Lpq[((wave * 4 + quad) * 4 + ni) * 16 + l16] = pq[ni];
  }
  __syncthreads();
  if (tid < 128) {
    int wn2 = tid >> 6, rem = tid & 63;
    int nni = rem >> 4, ll = rem & 15;
    int gn = n0 + wn2 * 64 + nni * 16 + ll;
    float s = 0.f, q = 0.f;
#pragma unroll
    for (int wv = 0; wv < 2; ++wv)
#pragma unroll
      for (int qd = 0; qd < 4; ++qd) {
        int w2 = wn2 * 2 + wv;
        s += Lps[((w2 * 4 + qd) * 4 + nni) * 16 + ll];
        q += Lpq[((w2 * 4 + qd) * 4 + nni) * 16 + ll];
      }
    psum[(size_t)blockIdx.x * 512 + gn] = s;
    psumsq[(size_t)blockIdx.x * 512 + gn] = q;
  }
}

// ---------------------------------------------------------------------------
// BN finalize: wave-per-channel (512 waves), variable slab count
__global__ __launch_bounds__(256) void bn_fin_k(
    const float* __restrict__ psum, const float* __restrict__ psumsq, int nslabs,
    const float* __restrict__ gamma, const float* __restrict__ beta,
    float* __restrict__ sc, float* __restrict__ sh) {
  int c = blockIdx.x * 4 + (threadIdx.x >> 6);   // 0..511
  int lane = threadIdx.x & 63;
  float s = 0.f, q = 0.f;
  for (int g = lane; g < nslabs; g += 64) {
    s += psum[g * 512 + c];
    q += psumsq[g * 512 + c];
  }
#pragma unroll
  for (int off = 32; off; off >>= 1) {
    s += __shfl_down(s, off);
    q += __shfl_down(q, off);
  }
  if (lane == 0) {
    float mean = s * (1.f / 32768.f);
    float var = fmaxf(q * (1.f / 32768.f) - mean * mean, 0.f);
    float inv = rsqrtf(var + 1e-5f);
    float scale = gamma[c] * inv;
    sc[c] = scale;
    sh[c] = beta[c] - mean * scale;
  }
}

// ---------------------------------------------------------------------------
// layer3 (BN fused via precomputed sc/sh) + fused attention coord-prep
// (frag + transposed-coords tables; lane-0-only, ~25 extra ops — replaces
// the cprep_k dispatch). r13 lesson: do NOT inline BN-coef computation here
// (per-thread prologue in a thread-per-tiny-task kernel cost 45us).
__global__ __launch_bounds__(256) void l3_k(const u16* __restrict__ h,
                                            const float* __restrict__ sc,
                                            const float* __restrict__ sh,
                                            const float* __restrict__ w3,
                                            const float* __restrict__ b3,
                                            float4* __restrict__ c4out,
                                            float* __restrict__ fout,
                                            u4v* __restrict__ frag,
                                            u16* __restrict__ ctg) {
  int wid = blockIdx.x * 4 + (threadIdx.x >> 6);
  int lane = threadIdx.x & 63;
  int k0 = lane * 8;
  uint4 hv = *(const uint4*)(h + (size_t)wid * 512 + k0);
  const u16* hp = (const u16*)&hv;
  float a0 = 0, a1 = 0, a2 = 0;
#pragma unroll
  for (int j = 0; j < 8; ++j) {
    int k = k0 + j;
    float x = fmaxf(fmaf(u2f(hp[j]), sc[k], sh[k]), 0.f);
    a0 = fmaf(x, w3[k], a0);
    a1 = fmaf(x, w3[512 + k], a1);
    a2 = fmaf(x, w3[1024 + k], a2);
  }
#pragma unroll
  for (int off = 32; off; off >>= 1) {
    a0 += __shfl_down(a0, off);
    a1 += __shfl_down(a1, off);
    a2 += __shfl_down(a2, off);
  }
  if (lane == 0) {
    a0 += b3[0]; a1 += b3[1]; a2 += b3[2];
    if (c4out) {
      float sq = a0 * a0 + a1 * a1 + a2 * a2;
      c4out[wid] = make_float4(a0, a1, a2, sq);
      // fused cprep: hi/lo bf16 A-frag + transposed PV coords (row0 = ones)
      float nhw = -0.5f * sq;
      u16 hx = f2u(a0), hy = f2u(a1), hz = f2u(a2), hw = f2u(nhw);
      u16 lx = f2u(a0 - u2f(hx)), ly = f2u(a1 - u2f(hy));
      u16 lz = f2u(a2 - u2f(hz)), lw = f2u(nhw - u2f(hw));
      u32 h01 = (u32)hx | ((u32)hy << 16), h23 = (u32)hz | ((u32)hw << 16);
      u32 l01 = (u32)lx | ((u32)ly << 16), l23 = (u32)lz | ((u32)lw << 16);
      frag[wid] = (u4v){h01, h23, l01, l23};
      int chunk = wid >> 5, p32 = wid & 31;
      u16* basep = ctg + (size_t)chunk * 128;    // 4 rows x 32 u16
      basep[p32] = 0x3F80;                       // ones row (c=0)
      basep[32 + p32] = hx;
      basep[64 + p32] = hy;
      basep[96 + p32] = hz;
    }
    if (fout) {
      fout[(size_t)wid * 3 + 0] = a0;
      fout[(size_t)wid * 3 + 1] = a1;
      fout[(size_t)wid * 3 + 2] = a2;
    }
  }
}

// ---------------------------------------------------------------------------
// MFMA flash attention. Block = 512 thr (8 waves), 32 queries/block (1024
// blocks). SIMD-issue-bound at ~45us (r11: occupancy 34->58% left time
// unchanged). Score tile 16p x 16q via mfma_16x16x32_bf16 with compensated
// hi/lo split in spare K-slots (fp32-grade mask). Point-side fragments
// precomputed (fused into l3). e values trunc-packed bf16 via wave-private
// LDS (80B-padded rows). PV B-frag from precomputed transposed coords.
__global__ __launch_bounds__(512) void attnm_k(const float4* __restrict__ c4,
                                               const u4v* __restrict__ frag,
                                               const u16* __restrict__ ctg,
                                               const float* __restrict__ G,
                                               const float* __restrict__ wv,
                                               u16* __restrict__ attnb) {
  // LDS: ebuf 8w*2560=20480 | fin 4096  => 24 KB
  __shared__ __align__(16) char lds[20480 + 4096];
  int wave = threadIdx.x >> 6, lane = threadIdx.x & 63;
  int g = lane >> 4, q16 = lane & 15;
  int qbase = blockIdx.x * 32;          // 32 consecutive queries, same batch
  int b = qbase >> 12;
  int pt0 = wave * 512;
  char* ebuf = lds + wave * 2560;       // 2 s-sets x 16 q x 80 B
  float* fin = (float*)(lds + 20480);
  int chunk0 = b * 128 + (pt0 >> 5);    // global 32-pt chunk base for this wave

  // ---- query-side B-frags (2 sets x 16 q) ----
  float Gr[9];
#pragma unroll
  for (int i = 0; i < 9; ++i) Gr[i] = G[i];
  u32 bh0[2], bh1[2], bh2[2], bh3[2];   // dm-B words
  u32 sh0[2], sh1[2], sh2[2], sh3[2];   // s2-B words
  float thr[2];
#pragma unroll
  for (int s = 0; s < 2; ++s) {
    float4 cq = c4[qbase + s * 16 + q16];
    thr[s] = 0.5f * (cq.w - R_ATT2);
    u16 hx = f2u(cq.x), hy = f2u(cq.y), hz = f2u(cq.z);
    u16 lx = f2u(cq.x - u2f(hx)), ly = f2u(cq.y - u2f(hy)), lz = f2u(cq.z - u2f(hz));
    u32 h01 = (u32)hx | ((u32)hy << 16);
    u32 h23 = (u32)hz | (0x3F80u << 16);     // [cz, 1.0]
    u32 l01 = (u32)lx | ((u32)ly << 16);
    u32 l23 = (u32)lz;                        // [lz, 0]
    bh0[s] = (g <= 1) ? h01 : 0u;
    bh1[s] = (g <= 1) ? h23 : 0u;
    bh2[s] = (g == 0) ? l01 : 0u;
    bh3[s] = (g == 0) ? l23 : 0u;
    const float SC = INV_SQRT_D * LOG2E;
    float g0v = (cq.x * Gr[0] + cq.y * Gr[3] + cq.z * Gr[6]) * SC;
    float g1v = (cq.x * Gr[1] + cq.y * Gr[4] + cq.z * Gr[7]) * SC;
    float g2v = (cq.x * Gr[2] + cq.y * Gr[5] + cq.z * Gr[8]) * SC;
    u16 ghx = f2u(g0v), ghy = f2u(g1v), ghz = f2u(g2v);
    u16 glx = f2u(g0v - u2f(ghx)), gly = f2u(g1v - u2f(ghy)), glz = f2u(g2v - u2f(ghz));
    u32 gh01 = (u32)ghx | ((u32)ghy << 16);
    u32 gh23 = (u32)ghz;                      // [gz, 0]
    u32 gl01 = (u32)glx | ((u32)gly << 16);
    u32 gl23 = (u32)glz;
    sh0[s] = (g <= 1) ? gh01 : 0u;
    sh1[s] = (g <= 1) ? gh23 : 0u;
    sh2[s] = (g == 0) ? gl01 : 0u;
    sh3[s] = (g == 0) ? gl23 : 0u;
  }

  f4v pvAcc[2];
#pragma unroll
  for (int s = 0; s < 2; ++s) pvAcc[s] = (f4v){0.f, 0.f, 0.f, 0.f};

  int csw = g ^ (q16 & 3);              // swizzled read chunk (PV A-frag)
  for (int w = 0; w < 16; ++w) {        // 16 windows x 32 pts
#pragma unroll
    for (int tp = 0; tp < 2; ++tp) {
      int p = pt0 + w * 32 + tp * 16 + q16;
      u4v f = frag[(size_t)b * NPTS + p];
      u32 a0 = (g == 0) ? f.x : ((g == 1) ? f.z : 0u);
      u32 a1 = (g == 0) ? f.y : ((g == 1) ? f.w : 0u);
      u32 a2 = (g == 0) ? f.x : 0u;
      u32 a3 = (g == 0) ? f.y : 0u;
      s8v av = mk8(a0, a1, a2, a3);
      int wsw = ((tp * 2 + (g >> 1)) ^ (q16 & 3)) * 16 + (g & 1) * 8;
#pragma unroll
      for (int s = 0; s < 2; ++s) {
        f4v z4 = (f4v){0.f, 0.f, 0.f, 0.f};
        f4v dmv = __builtin_amdgcn_mfma_f32_16x16x32_bf16(
            av, mk8(bh0[s], bh1[s], bh2[s], bh3[s]), z4, 0, 0, 0);
        f4v s2v = __builtin_amdgcn_mfma_f32_16x16x32_bf16(
            av, mk8(sh0[s], sh1[s], sh2[s], sh3[s]), z4, 0, 0, 0);
        float e0 = (dmv[0] >= thr[s]) ? fast_exp2(s2v[0]) : 0.f;
        float e1 = (dmv[1] >= thr[s]) ? fast_exp2(s2v[1]) : 0.f;
        float e2 = (dmv[2] >= thr[s]) ? fast_exp2(s2v[2]) : 0.f;
        float e3 = (dmv[3] >= thr[s]) ? fast_exp2(s2v[3]) : 0.f;
        u2v ew = (u2v){packtrunc(e0, e1), packtrunc(e2, e3)};
        *(u2v*)(ebuf + s * 1280 + q16 * 80 + wsw) = ew;
      }
    }
    // PV B-frag: lane (g, c=q16&3): coord row c of pts g*8..g*8+7 (row0=ones)
    const u16* ctb = ctg + (size_t)(chunk0 + w) * 128 + (q16 & 3) * 32 + g * 8;
    u4v bt = *(const u4v*)ctb;
    s8v pvB = mk8(bt.x, bt.y, bt.z, bt.w);
#pragma unroll
    for (int s = 0; s < 2; ++s) {
      u4v at = *(const u4v*)(ebuf + s * 1280 + q16 * 80 + csw * 16);
      pvAcc[s] = __builtin_amdgcn_mfma_f32_16x16x32_bf16(
          mk8(at.x, at.y, at.z, at.w), pvB, pvAcc[s], 0, 0, 0);
    }
  }

  // ---- combine 8 waves, normalize, project to attnb ----
  if (q16 < 4) {
#pragma unroll
    for (int s = 0; s < 2; ++s)
#pragma unroll
      for (int r = 0; r < 4; ++r)
        fin[wave * 128 + (s * 16 + g * 4 + r) * 4 + q16] = pvAcc[s][r];
  }
  __syncthreads();
  float* comb = (float*)lds;   // 128 floats, reuses ebuf region
  int t = threadIdx.x;
  if (t < 128) {
    int qb = t >> 2, c = t & 3;
    float acc = 0.f;
#pragma unroll
    for (int wv8 = 0; wv8 < 8; ++wv8) acc += fin[wv8 * 128 + qb * 4 + c];
    comb[qb * 4 + c] = acc;
  }
  __syncthreads();
#pragma unroll
  for (int it = 0; it < 4; ++it) {
    int task = t + it * 512;            // 2048 tasks: 32 q x 64 d-pairs
    int qb = task >> 6, dp = task & 63;
    float sw = comb[qb * 4 + 0];
    float sx = comb[qb * 4 + 1];
    float sy = comb[qb * 4 + 2];
    float sz = comb[qb * 4 + 3];
    float inv = 1.f / sw;
    float ox = sx * inv, oy = sy * inv, oz = sz * inv;
    int d0 = dp * 2;
    float v0 = ox * wv[d0 * 3] + oy * wv[d0 * 3 + 1] + oz * wv[d0 * 3 + 2];
    float v1 = ox * wv[d0 * 3 + 3] + oy * wv[d0 * 3 + 4] + oz * wv[d0 * 3 + 5];
    u32 pack = (u32)f2u(v0) | ((u32)f2u(v1) << 16);
    *(u32*)(attnb + (size_t)(qbase + qb) * 128 + d0) = pack;
  }
}

// ---------------------------------------------------------------------------
extern "C" void kernel_launch(void* const* d_in, const int* in_sizes, int n_in,
                              void* d_out, int out_size, void* d_ws, size_t ws_size,
                              hipStream_t stream) {
  const float* z = (const float*)d_in[0];
  const float* tmpl = (const float*)d_in[1];
  const float* wq = (const float*)d_in[2];
  const float* wk = (const float*)d_in[3];
  const float* wv = (const float*)d_in[4];
  const float* sw[3][10];
  for (int s = 0; s < 3; ++s)
    for (int j = 0; j < 10; ++j) sw[s][j] = (const float*)d_in[5 + s * 10 + j];
  // j: 0=w1 1=b1 2=g1 3=be1 4=w2 5=b2 6=g2 7=be2 8=w3 9=b3

  char* base = (char*)d_ws;
  size_t off = 0;
  auto alloc = [&](size_t bytes) -> void* {
    void* p = base + off;
    off = (off + bytes + 255) & ~(size_t)255;
    return p;
  };
  u16* hA = (u16*)alloc((size_t)ROWS * 512 * 2);        // 33.55 MB
  u16* hB = (u16*)alloc((size_t)ROWS * 512 * 2);        // 33.55 MB
  u16* attnb = (u16*)alloc((size_t)ROWS * 128 * 2);     //  8.39 MB
  float4* c4 = (float4*)alloc((size_t)ROWS * 16);       //  0.52 MB
  float* psum = (float*)alloc(2048 * 512 * 4);          //  4.19 MB (slabs)
  float* psumsq = (float*)alloc(2048 * 512 * 4);        //  4.19 MB
  float* zwbuf = (float*)alloc(4096 * 4);
  float* scv = (float*)alloc(512 * 4);
  float* shv = (float*)alloc(512 * 4);
  float* G = (float*)alloc(256);
  u16* w1abf = (u16*)alloc(512 * 128 * 2);
  u16* w2bf = (u16*)alloc(512 * 512 * 2);
  float* ubuf = (float*)alloc(1536 * 4);
  u4v* fragb = (u4v*)alloc((size_t)ROWS * 16);          //  0.52 MB
  u16* ctg = (u16*)alloc((size_t)1024 * 128 * 2);       //  0.26 MB

  gram_k<<<1, 64, 0, stream>>>(wq, wk, G);

  for (int s = 0; s < 3; ++s) {
    int ldw = (s == 0) ? 515 : 643;
    prep2_k<<<1024, 256, 0, stream>>>(z, sw[s][0], ldw, sw[s][1], sw[s][4],
                                      zwbuf, ubuf, w1abf, w2bf, s == 0 ? 0 : 1);
    if (s == 0) {
      // layer1 + slab BN stats
      s0l1s_k<<<2048, 256, 0, stream>>>(tmpl, ubuf, zwbuf, hA, psum, psumsq);
      bn_fin_k<<<128, 256, 0, stream>>>(psum, psumsq, 2048,
                                        sw[s][2], sw[s][3], scv, shv);
    } else {
      // GEMM1: h1 = attnb @ w1a^T + (zw + coords-rank3); slab h1 stats
      gemm_mfma_k<true><<<dim3(256, 4), 256, 0, stream>>>(
          attnb, 128, w1abf, 128, 128, nullptr, zwbuf, ubuf, c4,
          hA, psum, psumsq);
      bn_fin_k<<<128, 256, 0, stream>>>(psum, psumsq, 256,
                                        sw[s][2], sw[s][3], scv, shv);
    }
    // BN+ReLU in-place on hA, then GEMM2 with direct global_load_lds staging.
    bnrelu_k<<<2048, 256, 0, stream>>>(hA, scv, shv);
    gemm_mfma_k<false><<<dim3(256, 4), 256, 0, stream>>>(
        hA, 512, w2bf, 512, 512, sw[s][5], nullptr, nullptr, nullptr,
        hB, psum, psumsq);
    bn_fin_k<<<128, 256, 0, stream>>>(psum, psumsq, 256,
                                      sw[s][6], sw[s][7], scv, shv);
    bool last = (s == 2);
    // layer3 (sc/sh precomputed) + fused attention coord-prep
    l3_k<<<8192, 256, 0, stream>>>(hB, scv, shv, sw[s][8], sw[s][9],
                                   last ? nullptr : c4,
                                   last ? (float*)d_out : nullptr,
                                   fragb, ctg);
    if (!last) {
      attnm_k<<<1024, 512, 0, stream>>>(c4, fragb, ctg, G, wv, attnb);
    }
  }
}